// Round 1
// baseline (145.814 us; speedup 1.0000x reference)
//
#include <hip/hip_runtime.h>

#define NEGC (-1000000000.0f)

constexpr int B_ = 64;
constexpr int M_ = 16;
constexpr int L_ = 128;

// output offsets (in floats), concatenated in reference return order
constexpr long OFF_FTS = 0;                            // fwd_ts   (B,M,L)
constexpr long OFF_FMS = OFF_FTS + (long)B_*M_*L_;     // fwd_ms   (B,M,L)
constexpr long OFF_LA  = OFF_FMS + (long)B_*M_*L_;     // log_alpha (B,)
constexpr long OFF_ELA = OFF_LA + B_;                  // edge_log_alpha (B,M,L)
constexpr long OFF_LB  = OFF_ELA + (long)B_*M_*L_;     // log_betas (B,L)
constexpr long OFF_ELB = OFF_LB + (long)B_*L_;         // elb (B,L,M,L)
constexpr long OFF_ENT = OFF_ELB + (long)B_*L_*M_*L_;  // ent (B,)
constexpr long OFF_EE  = OFF_ENT + B_;                 // edge_ent (B,M,L)

__global__ __launch_bounds__(256) void tok_fused(
    const float* __restrict__ fwd_ts, const float* __restrict__ fwd_ms,
    const float* __restrict__ bwd_ts, const float* __restrict__ bwd_ms,
    const int* __restrict__ lengths, float* __restrict__ out)
{
  // +1 pad (129) -> 16 lanes hit 16 distinct banks on each step's ds_read
  __shared__ float lts[M_ * 129];
  __shared__ float lms[M_ * 129];
  const int tid = threadIdx.x;
  const int blk = blockIdx.x;
  const int m = tid & 15;

  if (blk < 512) {
    // ------- backward: 8192 sequences = (b, j). block = (b, 16 j's) -------
    const int b = blk >> 3;
    const int j = ((blk & 7) << 4) + (tid >> 4);

    // stage this b's bwd_ts / bwd_ms rows into LDS (coalesced float4 reads)
    const float4* gts = (const float4*)(bwd_ts + (long)b * M_ * L_);
    const float4* gms = (const float4*)(bwd_ms + (long)b * M_ * L_);
    #pragma unroll
    for (int it = 0; it < 2; ++it) {
      int t4 = it * 256 + tid;            // 0..511 float4s
      float4 a = gts[t4];
      float4 c = gms[t4];
      int mr = t4 >> 5;                   // row m (32 float4 per row)
      int l0 = (t4 * 4) & 127;
      float* dt = lts + mr * 129 + l0;
      dt[0] = a.x; dt[1] = a.y; dt[2] = a.z; dt[3] = a.w;
      float* dm = lms + mr * 129 + l0;
      dm[0] = c.x; dm[1] = c.y; dm[2] = c.z; dm[3] = c.w;
    }
    __syncthreads();

    const int i = 127 - j;
    const int thr = i + m;                // em = (l >= thr)
    const int lenm1 = lengths[b] - 1;
    float w = 0.0f;
    float la_keep = 0.0f;                 // la_all[0] = 0 fallback
    float* elb = out + OFF_ELB + ((long)(b * L_ + j) * M_ + m) * L_;
    const float* rowt = lts + m * 129;
    const float* rowm = lms + m * 129;

    for (int l0 = 0; l0 < L_; l0 += 4) {
      float tsv[4], msv[4], c4[4];
      #pragma unroll
      for (int k = 0; k < 4; ++k) { tsv[k] = rowt[l0 + k]; msv[k] = rowm[l0 + k]; }
      #pragma unroll
      for (int k = 0; k < 4; ++k) {
        const int l = l0 + k;
        const bool em = (l >= thr);
        // mm = em || m==0 ; m2 = mm && (ms==1) ; cand = em*ts + (m2 ? w : NEG)
        const bool usew = (em || m == 0) && (msv[k] > 0.5f);
        float cand = (em ? tsv[k] : 0.0f) + (usew ? w : NEGC);
        // 16-lane logsumexp
        float mx = cand;
        mx = fmaxf(mx, __shfl_xor(mx, 1, 16));
        mx = fmaxf(mx, __shfl_xor(mx, 2, 16));
        mx = fmaxf(mx, __shfl_xor(mx, 4, 16));
        mx = fmaxf(mx, __shfl_xor(mx, 8, 16));
        float s = __expf(cand - mx);
        float tot = s;
        tot += __shfl_xor(tot, 1, 16);
        tot += __shfl_xor(tot, 2, 16);
        tot += __shfl_xor(tot, 4, 16);
        tot += __shfl_xor(tot, 8, 16);
        float la = mx + __logf(tot);
        c4[k] = em ? cand : NEGC;         // elb = em ? cand : NEG
        if (l == lenm1) la_keep = la;
        // shift: w_new[m] = (m==0) ? la : w_old[m-1]
        float up = __shfl_up(w, 1, 16);
        w = (m == 0) ? la : up;
      }
      *(float4*)(elb + l0) = make_float4(c4[0], c4[1], c4[2], c4[3]);
    }
    if (m == 0) out[OFF_LB + (long)b * L_ + j] = la_keep;

  } else if (blk < 516) {
    // ------- forward + entropy: 64 sequences, 16 per block -------
    const int b = (blk - 512) * 16 + (tid >> 4);
    const int lenm1 = lengths[b] - 1;
    const float* fts = fwd_ts + (long)(b * M_ + m) * L_;
    const float* fms = fwd_ms + (long)(b * M_ + m) * L_;
    float w_la = 0.0f, w_h = 0.0f, la_keep = 0.0f, h_keep = 0.0f;
    float* ela = out + OFF_ELA + (long)(b * M_ + m) * L_;
    float* ee  = out + OFF_EE  + (long)(b * M_ + m) * L_;

    for (int j0 = 0; j0 < L_; j0 += 4) {
      float tsv[4], msv[4], c4[4], e4[4];
      #pragma unroll
      for (int k = 0; k < 4; ++k) { tsv[k] = fts[j0 + k]; msv[k] = fms[j0 + k]; }
      #pragma unroll
      for (int k = 0; k < 4; ++k) {
        const int j = j0 + k;
        const bool valid = msv[k] > 0.5f;
        float cand = tsv[k] + (valid ? w_la : NEGC);
        float mx = cand;
        mx = fmaxf(mx, __shfl_xor(mx, 1, 16));
        mx = fmaxf(mx, __shfl_xor(mx, 2, 16));
        mx = fmaxf(mx, __shfl_xor(mx, 4, 16));
        mx = fmaxf(mx, __shfl_xor(mx, 8, 16));
        float s = __expf(cand - mx);
        float tot = s;
        tot += __shfl_xor(tot, 1, 16);
        tot += __shfl_xor(tot, 2, 16);
        tot += __shfl_xor(tot, 4, 16);
        tot += __shfl_xor(tot, 8, 16);
        float la = mx + __logf(tot);
        // q = exp(cand - la) = s / tot ; contrib = q*(w_h + la - cand)
        float q = valid ? (s / tot) : 0.0f;
        float contrib = valid ? q * (w_h + la - cand) : 0.0f;
        float h = contrib;
        h += __shfl_xor(h, 1, 16);
        h += __shfl_xor(h, 2, 16);
        h += __shfl_xor(h, 4, 16);
        h += __shfl_xor(h, 8, 16);
        c4[k] = cand;
        e4[k] = contrib;
        if (j == lenm1) { la_keep = la; h_keep = h; }
        float upl = __shfl_up(w_la, 1, 16);
        float uph = __shfl_up(w_h, 1, 16);
        w_la = (m == 0) ? la : upl;
        w_h  = (m == 0) ? h  : uph;
      }
      *(float4*)(ela + j0) = make_float4(c4[0], c4[1], c4[2], c4[3]);
      *(float4*)(ee  + j0) = make_float4(e4[0], e4[1], e4[2], e4[3]);
    }
    if (m == 0) { out[OFF_LA + b] = la_keep; out[OFF_ENT + b] = h_keep; }

  } else {
    // ------- pass-through copies: fwd_ts -> out0, fwd_ms -> out1 -------
    const int cbk = blk - 516;            // 0..63
    const float4* s0 = (const float4*)fwd_ts;
    const float4* s1 = (const float4*)fwd_ms;
    float4* d = (float4*)out;
    for (int idx = cbk * 256 + tid; idx < 65536; idx += 64 * 256) {
      float4 v = (idx < 32768) ? s0[idx] : s1[idx - 32768];
      d[idx] = v;
    }
  }
}

extern "C" void kernel_launch(void* const* d_in, const int* in_sizes, int n_in,
                              void* d_out, int out_size, void* d_ws, size_t ws_size,
                              hipStream_t stream) {
  const float* fts = (const float*)d_in[0];
  const float* fms = (const float*)d_in[1];
  const float* bts = (const float*)d_in[2];
  const float* bms = (const float*)d_in[3];
  const int*   len = (const int*)d_in[4];
  float* out = (float*)d_out;
  // 512 backward blocks + 4 forward blocks + 64 copy blocks
  hipLaunchKernelGGL(tok_fused, dim3(580), dim3(256), 0, stream,
                     fts, fms, bts, bms, len, out);
}

// Round 2
// 140.987 us; speedup vs baseline: 1.0342x; 1.0342x over previous
//
#include <hip/hip_runtime.h>

#define NEGC (-1000000000.0f)

constexpr int B_ = 64;
constexpr int M_ = 16;
constexpr int L_ = 128;
constexpr int LDSS = 132;   // LDS row stride: %4==0 (float4 align), 2-way bank alias only (free)

// output offsets (floats), concatenated in reference return order
constexpr long OFF_FTS = 0;
constexpr long OFF_FMS = OFF_FTS + (long)B_*M_*L_;
constexpr long OFF_LA  = OFF_FMS + (long)B_*M_*L_;
constexpr long OFF_ELA = OFF_LA + B_;
constexpr long OFF_LB  = OFF_ELA + (long)B_*M_*L_;
constexpr long OFF_ELB = OFF_LB + (long)B_*L_;
constexpr long OFF_ENT = OFF_ELB + (long)B_*L_*M_*L_;
constexpr long OFF_EE  = OFF_ENT + B_;

// ---- DPP helpers: 16-lane (row) cross-lane at VALU latency, no LDS pipe ----
template<int CTRL>
__device__ __forceinline__ float dppf(float x) {
  return __int_as_float(__builtin_amdgcn_update_dpp(
      0, __float_as_int(x), CTRL, 0xF, 0xF, true));
}
// allreduce max over 16-lane row: xor1(quad), xor2(quad), half_mirror, mirror
__device__ __forceinline__ float row_max16(float x) {
  x = fmaxf(x, dppf<0xB1>(x));    // quad_perm [1,0,3,2]
  x = fmaxf(x, dppf<0x4E>(x));    // quad_perm [2,3,0,1]
  x = fmaxf(x, dppf<0x141>(x));   // row_half_mirror
  x = fmaxf(x, dppf<0x140>(x));   // row_mirror
  return x;
}
__device__ __forceinline__ float row_sum16(float x) {
  x += dppf<0xB1>(x);
  x += dppf<0x4E>(x);
  x += dppf<0x141>(x);
  x += dppf<0x140>(x);
  return x;
}
// lane m gets lane m-1's value (lane 0 -> 0.0f, overridden by cndmask anyway)
__device__ __forceinline__ float row_shr1(float x) { return dppf<0x111>(x); }

__global__ __launch_bounds__(256) void tok_fused(
    const float* __restrict__ fwd_ts, const float* __restrict__ fwd_ms,
    const float* __restrict__ bwd_ts, const float* __restrict__ bwd_ms,
    const int* __restrict__ lengths, float* __restrict__ out)
{
  __shared__ float lts[M_ * LDSS];
  __shared__ float lms[M_ * LDSS];
  const int tid = threadIdx.x;
  const int blk = blockIdx.x;
  const int m = tid & 15;

  if (blk < 512) {
    // ---- backward: 8192 seqs = (b, j). block = (b, j ≡ k mod 8) for balance ----
    const int b = blk >> 3;
    const int k = blk & 7;
    const int g = tid >> 4;              // 16-lane group 0..15
    const int j = k + (g << 3);          // j ∈ {k, k+8, ..., k+120}
    const int wv = tid >> 6;             // wave in block 0..3
    const int jmax = k + ((wv * 4 + 3) << 3);      // largest j in this wave
    const int l_start = (127 - jmax) & ~15;        // wave-uniform, 16-aligned

    // stage this b's bwd_ts / bwd_ms into LDS (coalesced float4)
    const float4* gts = (const float4*)(bwd_ts + (long)b * M_ * L_);
    const float4* gms = (const float4*)(bwd_ms + (long)b * M_ * L_);
    #pragma unroll
    for (int it = 0; it < 2; ++it) {
      int t4 = it * 256 + tid;           // 0..511 float4s
      int mr = t4 >> 5;
      int l4 = (t4 & 31) << 2;
      *(float4*)(lts + mr * LDSS + l4) = gts[t4];
      *(float4*)(lms + mr * LDSS + l4) = gms[t4];
    }
    __syncthreads();

    const int i = 127 - j;
    const int thr = i + m;               // em = (l >= thr)
    const int lenm1 = lengths[b] - 1;
    float w = 0.0f;
    float la_keep = 0.0f;                // exact: la==0 in trivial region
    float* elb = out + OFF_ELB + ((long)(b * L_ + j) * M_ + m) * L_;
    const float* rowt = lts + m * LDSS;
    const float* rowm = lms + m * LDSS;

    // trivial region l < l_start: w stays 0, elb = NEG (streaming, line-merged)
    const float4 negv = make_float4(NEGC, NEGC, NEGC, NEGC);
    for (int l = 0; l < l_start; l += 4) *(float4*)(elb + l) = negv;

    for (int l0 = l_start; l0 < L_; l0 += 16) {
      float c16[16];
      #pragma unroll
      for (int q = 0; q < 4; ++q) {
        const int lb = l0 + q * 4;
        float4 tsv = *(const float4*)(rowt + lb);
        float4 msv = *(const float4*)(rowm + lb);
        float ta[4] = {tsv.x, tsv.y, tsv.z, tsv.w};
        float ma[4] = {msv.x, msv.y, msv.z, msv.w};
        #pragma unroll
        for (int kk = 0; kk < 4; ++kk) {
          const int l = lb + kk;
          const bool em = (l >= thr);
          const bool usew = (em || m == 0) && (ma[kk] > 0.5f);
          float cand = (em ? ta[kk] : 0.0f) + (usew ? w : NEGC);
          float mx = row_max16(cand);
          float s = __expf(cand - mx);
          float tot = row_sum16(s);
          float la = mx + __logf(tot);
          c16[q * 4 + kk] = em ? cand : NEGC;
          if (l == lenm1) la_keep = la;
          float up = row_shr1(w);
          w = (m == 0) ? la : up;
        }
      }
      float4* dst = (float4*)(elb + l0);
      dst[0] = make_float4(c16[0],  c16[1],  c16[2],  c16[3]);
      dst[1] = make_float4(c16[4],  c16[5],  c16[6],  c16[7]);
      dst[2] = make_float4(c16[8],  c16[9],  c16[10], c16[11]);
      dst[3] = make_float4(c16[12], c16[13], c16[14], c16[15]);
    }
    if (m == 0) out[OFF_LB + (long)b * L_ + j] = la_keep;

  } else if (blk < 516) {
    // ---- forward + entropy: 64 sequences, 16 per block ----
    const int b = (blk - 512) * 16 + (tid >> 4);
    const int lenm1 = lengths[b] - 1;
    const float* fts = fwd_ts + (long)(b * M_ + m) * L_;
    const float* fms = fwd_ms + (long)(b * M_ + m) * L_;
    float w_la = 0.0f, w_h = 0.0f, la_keep = 0.0f, h_keep = 0.0f;
    float* ela = out + OFF_ELA + (long)(b * M_ + m) * L_;
    float* ee  = out + OFF_EE  + (long)(b * M_ + m) * L_;

    for (int j0 = 0; j0 < L_; j0 += 16) {
      float c16[16], e16[16];
      #pragma unroll
      for (int q = 0; q < 4; ++q) {
        const int jb = j0 + q * 4;
        float4 tsv = *(const float4*)(fts + jb);
        float4 msv = *(const float4*)(fms + jb);
        float ta[4] = {tsv.x, tsv.y, tsv.z, tsv.w};
        float ma[4] = {msv.x, msv.y, msv.z, msv.w};
        #pragma unroll
        for (int kk = 0; kk < 4; ++kk) {
          const int j = jb + kk;
          const bool valid = ma[kk] > 0.5f;
          float cand = ta[kk] + (valid ? w_la : NEGC);
          float mx = row_max16(cand);
          float s = __expf(cand - mx);
          float tot = row_sum16(s);
          float la = mx + __logf(tot);
          float q_ = valid ? (s / tot) : 0.0f;
          float contrib = valid ? q_ * (w_h + la - cand) : 0.0f;
          float h = row_sum16(contrib);
          c16[q * 4 + kk] = cand;
          e16[q * 4 + kk] = contrib;
          if (j == lenm1) { la_keep = la; h_keep = h; }
          float upl = row_shr1(w_la);
          float uph = row_shr1(w_h);
          w_la = (m == 0) ? la : upl;
          w_h  = (m == 0) ? h  : uph;
        }
      }
      float4* d0 = (float4*)(ela + j0);
      d0[0] = make_float4(c16[0],  c16[1],  c16[2],  c16[3]);
      d0[1] = make_float4(c16[4],  c16[5],  c16[6],  c16[7]);
      d0[2] = make_float4(c16[8],  c16[9],  c16[10], c16[11]);
      d0[3] = make_float4(c16[12], c16[13], c16[14], c16[15]);
      float4* d1 = (float4*)(ee + j0);
      d1[0] = make_float4(e16[0],  e16[1],  e16[2],  e16[3]);
      d1[1] = make_float4(e16[4],  e16[5],  e16[6],  e16[7]);
      d1[2] = make_float4(e16[8],  e16[9],  e16[10], e16[11]);
      d1[3] = make_float4(e16[12], e16[13], e16[14], e16[15]);
    }
    if (m == 0) { out[OFF_LA + b] = la_keep; out[OFF_ENT + b] = h_keep; }

  } else {
    // ---- pass-through copies: fwd_ts -> out0, fwd_ms -> out1 ----
    const int cbk = blk - 516;           // 0..63
    const float4* s0 = (const float4*)fwd_ts;
    const float4* s1 = (const float4*)fwd_ms;
    float4* d = (float4*)out;
    for (int idx = cbk * 256 + tid; idx < 65536; idx += 64 * 256) {
      float4 v = (idx < 32768) ? s0[idx] : s1[idx - 32768];
      d[idx] = v;
    }
  }
}

extern "C" void kernel_launch(void* const* d_in, const int* in_sizes, int n_in,
                              void* d_out, int out_size, void* d_ws, size_t ws_size,
                              hipStream_t stream) {
  const float* fts = (const float*)d_in[0];
  const float* fms = (const float*)d_in[1];
  const float* bts = (const float*)d_in[2];
  const float* bms = (const float*)d_in[3];
  const int*   len = (const int*)d_in[4];
  float* out = (float*)d_out;
  hipLaunchKernelGGL(tok_fused, dim3(580), dim3(256), 0, stream,
                     fts, fms, bts, bms, len, out);
}

// Round 3
// 115.364 us; speedup vs baseline: 1.2639x; 1.2221x over previous
//
#include <hip/hip_runtime.h>

#define NEGC (-1000000000.0f)

constexpr int B_ = 64;
constexpr int M_ = 16;
constexpr int L_ = 128;
constexpr int LDSS = 132;   // staging row stride
constexpr int TROW = 21;    // transpose-tile row stride (16 distinct banks over m)
constexpr int TSZ  = 336;   // tile stride: %32 == 16 -> adjacent groups use disjoint bank halves

// output offsets (floats), reference return order
constexpr long OFF_FTS = 0;
constexpr long OFF_FMS = OFF_FTS + (long)B_*M_*L_;
constexpr long OFF_LA  = OFF_FMS + (long)B_*M_*L_;
constexpr long OFF_ELA = OFF_LA + B_;
constexpr long OFF_LB  = OFF_ELA + (long)B_*M_*L_;
constexpr long OFF_ELB = OFF_LB + (long)B_*L_;
constexpr long OFF_ENT = OFF_ELB + (long)B_*L_*M_*L_;
constexpr long OFF_EE  = OFF_ENT + B_;

// ---- DPP helpers: 16-lane cross-lane at VALU latency ----
template<int CTRL>
__device__ __forceinline__ float dppf(float x) {
  return __int_as_float(__builtin_amdgcn_update_dpp(
      0, __float_as_int(x), CTRL, 0xF, 0xF, true));
}
__device__ __forceinline__ float row_max16(float x) {
  x = fmaxf(x, dppf<0xB1>(x));
  x = fmaxf(x, dppf<0x4E>(x));
  x = fmaxf(x, dppf<0x141>(x));
  x = fmaxf(x, dppf<0x140>(x));
  return x;
}
__device__ __forceinline__ float row_sum16(float x) {
  x += dppf<0xB1>(x);
  x += dppf<0x4E>(x);
  x += dppf<0x141>(x);
  x += dppf<0x140>(x);
  return x;
}
__device__ __forceinline__ float row_shr1(float x) { return dppf<0x111>(x); }

__global__ __launch_bounds__(256) void tok_fused(
    const float* __restrict__ fwd_ts, const float* __restrict__ fwd_ms,
    const float* __restrict__ bwd_ts, const float* __restrict__ bwd_ms,
    const int* __restrict__ lengths, float* __restrict__ out)
{
  __shared__ float lts[M_ * LDSS];
  __shared__ float lms[M_ * LDSS];
  __shared__ float tls[16 * TSZ];        // 16 group-tiles (16 m x 16 l, stride 21)
  const int tid = threadIdx.x;
  const int blk = blockIdx.x;
  const int m = tid & 15;

  if (blk < 512) {
    // ---- backward: 8192 seqs = (b, j). block = (b, j ≡ k mod 8) ----
    const int b = blk >> 3;
    const int k = blk & 7;
    const int gg = tid >> 4;             // 16-lane group 0..15
    const int j = k + (gg << 3);
    const int wv = tid >> 6;             // wave 0..3
    const int lane = tid & 63;
    const int jmax = k + ((wv * 4 + 3) << 3);
    const int l_start = (127 - jmax) & ~15;   // wave-uniform, 16-aligned

    // stage b's bwd_ts / bwd_ms into LDS (coalesced float4)
    const float4* gts = (const float4*)(bwd_ts + (long)b * M_ * L_);
    const float4* gms = (const float4*)(bwd_ms + (long)b * M_ * L_);
    #pragma unroll
    for (int it = 0; it < 2; ++it) {
      int t4 = it * 256 + tid;
      int mr = t4 >> 5;
      int l4 = (t4 & 31) << 2;
      *(float4*)(lts + mr * LDSS + l4) = gts[t4];
      *(float4*)(lms + mr * LDSS + l4) = gms[t4];
    }

    // coalesced-store lane pattern: lane -> (sm, sc) covers a 16m x 16l tile
    const int sm = lane >> 2;            // store row (m)
    const int sc = (lane & 3) << 2;      // store col base (l within 16)

    // ---- Phase A: NEG prefill, full-line cooperative stores ----
    // region l < l_start has elb == NEG exactly (w stays 0 there)
    const float4 negv = make_float4(NEGC, NEGC, NEGC, NEGC);
    #pragma unroll
    for (int qq = 0; qq < 4; ++qq) {
      const int jq = k + ((wv * 4 + qq) << 3);
      float* basep = out + OFF_ELB + ((long)(b * L_ + jq) * M_ + sm) * L_ + sc;
      for (int l0 = 0; l0 < l_start; l0 += 16)
        *(float4*)(basep + l0) = negv;
    }

    __syncthreads();

    const int i = 127 - j;
    const int thr = i + m;               // em = (l >= thr)
    const int lenm1 = lengths[b] - 1;
    float w = 0.0f;
    float la_keep = 0.0f;                // exact: la == 0 in trivial region
    const float* rowt = lts + m * LDSS;
    const float* rowm = lms + m * LDSS;
    float* tb = tls + gg * TSZ + m * TROW;   // this lane's tile row

    for (int l0 = l_start; l0 < L_; l0 += 16) {
      #pragma unroll
      for (int q = 0; q < 4; ++q) {
        const int lb = l0 + q * 4;
        float4 tsv = *(const float4*)(rowt + lb);
        float4 msv = *(const float4*)(rowm + lb);
        float ta[4] = {tsv.x, tsv.y, tsv.z, tsv.w};
        float ma[4] = {msv.x, msv.y, msv.z, msv.w};
        #pragma unroll
        for (int kk = 0; kk < 4; ++kk) {
          const int l = lb + kk;
          const bool em = (l >= thr);
          const bool usew = (em || m == 0) && (ma[kk] > 0.5f);
          float cand = (em ? ta[kk] : 0.0f) + (usew ? w : NEGC);
          float mx = row_max16(cand);
          float s = __expf(cand - mx);
          float tot = row_sum16(s);
          float la = mx + __logf(tot);
          tb[q * 4 + kk] = em ? cand : NEGC;   // LDS tile write (off-chain)
          if (l == lenm1) la_keep = la;
          float up = row_shr1(w);
          w = (m == 0) ? la : up;
        }
      }
      // ---- flush 4 tiles via LDS transpose -> full-line coalesced stores ----
      // same-wave LDS write->read: no barrier needed (lgkmcnt ordering)
      #pragma unroll
      for (int qq = 0; qq < 4; ++qq) {
        const float* tq = tls + (wv * 4 + qq) * TSZ + sm * TROW + sc;
        float4 v = make_float4(tq[0], tq[1], tq[2], tq[3]);
        const int jq = k + ((wv * 4 + qq) << 3);
        float* dstb = out + OFF_ELB + ((long)(b * L_ + jq) * M_ + sm) * L_ + l0 + sc;
        *(float4*)dstb = v;
      }
    }
    if (m == 0) out[OFF_LB + (long)b * L_ + j] = la_keep;

  } else if (blk < 516) {
    // ---- forward + entropy: 64 sequences, 16 per block ----
    const int b = (blk - 512) * 16 + (tid >> 4);
    const int lenm1 = lengths[b] - 1;
    const float* fts = fwd_ts + (long)(b * M_ + m) * L_;
    const float* fms = fwd_ms + (long)(b * M_ + m) * L_;
    float w_la = 0.0f, w_h = 0.0f, la_keep = 0.0f, h_keep = 0.0f;
    float* ela = out + OFF_ELA + (long)(b * M_ + m) * L_;
    float* ee  = out + OFF_EE  + (long)(b * M_ + m) * L_;

    for (int j0 = 0; j0 < L_; j0 += 16) {
      float c16[16], e16[16];
      #pragma unroll
      for (int q = 0; q < 4; ++q) {
        const int jb = j0 + q * 4;
        float4 tsv = *(const float4*)(fts + jb);
        float4 msv = *(const float4*)(fms + jb);
        float ta[4] = {tsv.x, tsv.y, tsv.z, tsv.w};
        float ma[4] = {msv.x, msv.y, msv.z, msv.w};
        #pragma unroll
        for (int kk = 0; kk < 4; ++kk) {
          const int j = jb + kk;
          const bool valid = ma[kk] > 0.5f;
          float cand = ta[kk] + (valid ? w_la : NEGC);
          float mx = row_max16(cand);
          float s = __expf(cand - mx);
          float tot = row_sum16(s);
          float la = mx + __logf(tot);
          float q_ = valid ? (s / tot) : 0.0f;
          float contrib = valid ? q_ * (w_h + la - cand) : 0.0f;
          float h = row_sum16(contrib);
          c16[q * 4 + kk] = cand;
          e16[q * 4 + kk] = contrib;
          if (j == lenm1) { la_keep = la; h_keep = h; }
          float upl = row_shr1(w_la);
          float uph = row_shr1(w_h);
          w_la = (m == 0) ? la : upl;
          w_h  = (m == 0) ? h  : uph;
        }
      }
      float4* d0 = (float4*)(ela + j0);
      d0[0] = make_float4(c16[0],  c16[1],  c16[2],  c16[3]);
      d0[1] = make_float4(c16[4],  c16[5],  c16[6],  c16[7]);
      d0[2] = make_float4(c16[8],  c16[9],  c16[10], c16[11]);
      d0[3] = make_float4(c16[12], c16[13], c16[14], c16[15]);
      float4* d1 = (float4*)(ee + j0);
      d1[0] = make_float4(e16[0],  e16[1],  e16[2],  e16[3]);
      d1[1] = make_float4(e16[4],  e16[5],  e16[6],  e16[7]);
      d1[2] = make_float4(e16[8],  e16[9],  e16[10], e16[11]);
      d1[3] = make_float4(e16[12], e16[13], e16[14], e16[15]);
    }
    if (m == 0) { out[OFF_LA + b] = la_keep; out[OFF_ENT + b] = h_keep; }

  } else {
    // ---- pass-through copies: fwd_ts -> out0, fwd_ms -> out1 ----
    const int cbk = blk - 516;
    const float4* s0 = (const float4*)fwd_ts;
    const float4* s1 = (const float4*)fwd_ms;
    float4* d = (float4*)out;
    for (int idx = cbk * 256 + tid; idx < 65536; idx += 64 * 256) {
      float4 v = (idx < 32768) ? s0[idx] : s1[idx - 32768];
      d[idx] = v;
    }
  }
}

extern "C" void kernel_launch(void* const* d_in, const int* in_sizes, int n_in,
                              void* d_out, int out_size, void* d_ws, size_t ws_size,
                              hipStream_t stream) {
  const float* fts = (const float*)d_in[0];
  const float* fms = (const float*)d_in[1];
  const float* bts = (const float*)d_in[2];
  const float* bms = (const float*)d_in[3];
  const int*   len = (const int*)d_in[4];
  float* out = (float*)d_out;
  hipLaunchKernelGGL(tok_fused, dim3(580), dim3(256), 0, stream,
                     fts, fms, bts, bms, len, out);
}